// Round 11
// baseline (1033.048 us; speedup 1.0000x reference)
//
#include <hip/hip_runtime.h>
#include <hip/hip_fp16.h>

#define EMBED 128
#define NRBF 6
#define VOCAB 100
#define EBLOCK 1024
#define GROUPS 32                   // 32-lane groups per block
#define CPG 19                      // edges per group per half
#define HALF_E (GROUPS * CPG)       // 608
#define BCHUNK (2 * HALF_E)         // 1216
#define T_HALFS (VOCAB * EMBED)                            // 12800 halfs/table
#define TABLE_BYTES (2 * T_HALFS * 2 + NRBF * EMBED * 4)   // 54,272 B
#define SMEM_BYTES (TABLE_BYTES + HALF_E * 16)             // 64,000 B

// ---------------------------------------------------------------------------
// Precompute (206 blocks): T1h/T2h fp16 tables (+bias folded), Wc fp32.
// ---------------------------------------------------------------------------
__global__ __launch_bounds__(EMBED) void precompute_kernel(
    const float* __restrict__ W_edge,
    const float* __restrict__ emb,
    const float* __restrict__ Wd,
    const float* __restrict__ b,
    __half* __restrict__ T1h,
    __half* __restrict__ T2h,
    float* __restrict__ Wc)
{
    const int d = threadIdx.x;
    const int v = blockIdx.x;
    if (v < 2 * VOCAB) {
        const int row = (v < VOCAB) ? v : v - VOCAB;
        const int woff = (v < VOCAB) ? 0 : EMBED;
        __shared__ float hrow[EMBED];
        hrow[d] = emb[row * EMBED + d];
        __syncthreads();
        float acc = (v < VOCAB) ? b[d] : 0.0f;
        #pragma unroll 8
        for (int j = 0; j < EMBED; ++j)
            acc += hrow[j] * Wd[(woff + j) * EMBED + d];
        if (v < VOCAB) T1h[row * EMBED + d] = __float2half_rn(acc);
        else           T2h[row * EMBED + d] = __float2half_rn(acc);
    } else {
        const int k = v - 2 * VOCAB;
        float acc = 0.0f;
        #pragma unroll 8
        for (int j = 0; j < EMBED; ++j)
            acc += W_edge[k * EMBED + j] * Wd[(2 * EMBED + j) * EMBED + d];
        Wc[k * EMBED + d] = acc;
    }
}

// ---------------------------------------------------------------------------
// v_store: stores only, SAME geometry (64 KB dyn LDS, 1024 thr) -> measures
// the pure store floor at the current occupancy. R passes.
// ---------------------------------------------------------------------------
__global__ __launch_bounds__(EBLOCK, 8) void v_store(
    float* __restrict__ out, int E, int R)
{
    extern __shared__ char smemraw[];
    (void)smemraw;
    const int tid  = threadIdx.x;
    const int base = blockIdx.x * BCHUNK;
    const int lane = tid & 31;
    const int d    = lane * 4;
    const int g    = tid >> 5;
    const int lb   = (g >> 1) * (2 * CPG) + (g & 1);

    for (int r = 0; r < R; ++r) {
        const float4 v = make_float4((float)(d + r), 1.f, 2.f, 3.f);
        for (int h = 0; h < 2; ++h) {
            const int ebase = base + h * HALF_E;
            #pragma unroll
            for (int i = 0; i < CPG; ++i) {
                const int e = ebase + lb + 2 * i;
                if (e < E)
                    *reinterpret_cast<float4*>(out + (long)e * EMBED + d) = v;
            }
        }
        asm volatile("" ::: "memory");
    }
}

// ---------------------------------------------------------------------------
// Shared staging helper for the full/noexp variants.
// ---------------------------------------------------------------------------
__device__ __forceinline__ void stage_tables(const float* tables, char* smemraw, int tid)
{
    const float4* src = reinterpret_cast<const float4*>(tables);
    float4* dst = reinterpret_cast<float4*>(smemraw);
    #pragma unroll 2
    for (int i = tid; i < TABLE_BYTES / 16; i += EBLOCK)
        dst[i] = src[i];
}

__device__ __forceinline__ void stage_half(
    const float* e_rbf, const int* z, const int* nbr,
    uint4* meta, int ebase, int tid, int E)
{
    if (tid < HALF_E) {
        const int e = ebase + tid;
        uint4 m = make_uint4(0u, 0u, 0u, 0u);
        if (e < E) {
            const int2 nn = *reinterpret_cast<const int2*>(nbr + 2 * e);
            const float* rp = e_rbf + (long)e * NRBF;
            const float2 a  = *reinterpret_cast<const float2*>(rp + 0);
            const float2 bb = *reinterpret_cast<const float2*>(rp + 2);
            const float2 c  = *reinterpret_cast<const float2*>(rp + 4);
            __half2 ha = __float22half2_rn(a);
            __half2 hb = __float22half2_rn(bb);
            __half2 hc = __float22half2_rn(c);
            m.x = *reinterpret_cast<unsigned*>(&ha);
            m.y = *reinterpret_cast<unsigned*>(&hb);
            m.z = *reinterpret_cast<unsigned*>(&hc);
            m.w = (unsigned)z[nn.x] | ((unsigned)z[nn.y] << 16);
        }
        meta[tid] = m;
    }
}

// ---------------------------------------------------------------------------
// The real consume body; SILU selects the activation (1) or raw acc (0).
// ---------------------------------------------------------------------------
template <int SILU>
__device__ __forceinline__ void consume_half(
    const __half* T1s, const __half* T2s, const uint4* meta,
    const float4& wc0, const float4& wc1, const float4& wc2,
    const float4& wc3, const float4& wc4, const float4& wc5,
    float* out, int ebase, int g, int d, int E)
{
    const int lb = (g >> 1) * (2 * CPG) + (g & 1);
    #pragma unroll
    for (int i = 0; i < CPG; ++i) {
        const int le = lb + 2 * i;
        const int e = ebase + le;

        const uint4 m = meta[le];
        const int za = (int)(m.w & 0xffffu) << 7;
        const int zb = (int)(m.w >> 16) << 7;

        const uint2 t1p = *reinterpret_cast<const uint2*>(T1s + za + d);
        const uint2 t2p = *reinterpret_cast<const uint2*>(T2s + zb + d);
        const __half2 s0 = __hadd2(*reinterpret_cast<const __half2*>(&t1p.x),
                                   *reinterpret_cast<const __half2*>(&t2p.x));
        const __half2 s1 = __hadd2(*reinterpret_cast<const __half2*>(&t1p.y),
                                   *reinterpret_cast<const __half2*>(&t2p.y));
        const float2 a01 = __half22float2(s0);
        const float2 a23 = __half22float2(s1);
        float4 acc = make_float4(a01.x, a01.y, a23.x, a23.y);

        const float2 f01 = __half22float2(*reinterpret_cast<const __half2*>(&m.x));
        const float2 f23 = __half22float2(*reinterpret_cast<const __half2*>(&m.y));
        const float2 f45 = __half22float2(*reinterpret_cast<const __half2*>(&m.z));

        acc.x += f01.x * wc0.x; acc.y += f01.x * wc0.y; acc.z += f01.x * wc0.z; acc.w += f01.x * wc0.w;
        acc.x += f01.y * wc1.x; acc.y += f01.y * wc1.y; acc.z += f01.y * wc1.z; acc.w += f01.y * wc1.w;
        acc.x += f23.x * wc2.x; acc.y += f23.x * wc2.y; acc.z += f23.x * wc2.z; acc.w += f23.x * wc2.w;
        acc.x += f23.y * wc3.x; acc.y += f23.y * wc3.y; acc.z += f23.y * wc3.z; acc.w += f23.y * wc3.w;
        acc.x += f45.x * wc4.x; acc.y += f45.x * wc4.y; acc.z += f45.x * wc4.z; acc.w += f45.x * wc4.w;
        acc.x += f45.y * wc5.x; acc.y += f45.y * wc5.y; acc.z += f45.y * wc5.z; acc.w += f45.y * wc5.w;

        float4 rr;
        if (SILU) {
            rr.x = acc.x * __builtin_amdgcn_rcpf(1.0f + __expf(-acc.x));
            rr.y = acc.y * __builtin_amdgcn_rcpf(1.0f + __expf(-acc.y));
            rr.z = acc.z * __builtin_amdgcn_rcpf(1.0f + __expf(-acc.z));
            rr.w = acc.w * __builtin_amdgcn_rcpf(1.0f + __expf(-acc.w));
        } else {
            rr = acc;
        }

        if (e < E)
            *reinterpret_cast<float4*>(out + (long)e * EMBED + d) = rr;
    }
}

template <int SILU>
__device__ __forceinline__ void edge_body(
    const float* e_rbf, const int* z, const int* nbr,
    const float* tables, float* out, int E, int R)
{
    extern __shared__ char smemraw[];
    __half* T1s = (__half*)smemraw;
    __half* T2s = T1s + T_HALFS;
    float*  Wcs = (float*)(smemraw + 2 * T_HALFS * 2);
    uint4*  meta = (uint4*)(smemraw + TABLE_BYTES);

    const int tid  = threadIdx.x;
    const int base = blockIdx.x * BCHUNK;
    const int lane = tid & 31;
    const int d    = lane * 4;
    const int g    = tid >> 5;

    stage_tables(tables, smemraw, tid);
    __syncthreads();

    const float4 wc0 = *reinterpret_cast<const float4*>(Wcs + 0 * EMBED + d);
    const float4 wc1 = *reinterpret_cast<const float4*>(Wcs + 1 * EMBED + d);
    const float4 wc2 = *reinterpret_cast<const float4*>(Wcs + 2 * EMBED + d);
    const float4 wc3 = *reinterpret_cast<const float4*>(Wcs + 3 * EMBED + d);
    const float4 wc4 = *reinterpret_cast<const float4*>(Wcs + 4 * EMBED + d);
    const float4 wc5 = *reinterpret_cast<const float4*>(Wcs + 5 * EMBED + d);

    for (int r = 0; r < R; ++r) {
        stage_half(e_rbf, z, nbr, meta, base, tid, E);
        __syncthreads();
        consume_half<SILU>(T1s, T2s, meta, wc0, wc1, wc2, wc3, wc4, wc5,
                           out, base, g, d, E);
        __syncthreads();
        stage_half(e_rbf, z, nbr, meta, base + HALF_E, tid, E);
        __syncthreads();
        consume_half<SILU>(T1s, T2s, meta, wc0, wc1, wc2, wc3, wc4, wc5,
                           out, base + HALF_E, g, d, E);
        __syncthreads();
        asm volatile("" ::: "memory");
    }
}

__global__ __launch_bounds__(EBLOCK, 8) void v_noexp(
    const float* __restrict__ e_rbf, const int* __restrict__ z,
    const int* __restrict__ nbr, const float* __restrict__ tables,
    float* __restrict__ out, int E, int R)
{
    edge_body<0>(e_rbf, z, nbr, tables, out, E, R);
}

__global__ __launch_bounds__(EBLOCK, 8) void v_full(
    const float* __restrict__ e_rbf, const int* __restrict__ z,
    const int* __restrict__ nbr, const float* __restrict__ tables,
    float* __restrict__ out, int E, int R)
{
    edge_body<1>(e_rbf, z, nbr, tables, out, E, R);
}

extern "C" void kernel_launch(void* const* d_in, const int* in_sizes, int n_in,
                              void* d_out, int out_size, void* d_ws, size_t ws_size,
                              hipStream_t stream)
{
    // Input order: e_rbf, z, nbr_list, W_edge, emb_table, W_dense, b_dense
    const float* e_rbf  = (const float*)d_in[0];
    const int*   z      = (const int*)  d_in[1];
    const int*   nbr    = (const int*)  d_in[2];
    const float* W_edge = (const float*)d_in[3];
    const float* emb    = (const float*)d_in[4];
    const float* Wd     = (const float*)d_in[5];
    const float* b      = (const float*)d_in[6];
    float* out = (float*)d_out;

    const int E = in_sizes[2] / 2;

    __half* T1h = (__half*)d_ws;
    __half* T2h = T1h + T_HALFS;
    float*  Wc  = (float*)((char*)d_ws + 2 * T_HALFS * 2);

    precompute_kernel<<<2 * VOCAB + NRBF, EMBED, 0, stream>>>(W_edge, emb, Wd, b, T1h, T2h, Wc);

    const int grid = (E + BCHUNK - 1) / BCHUNK;   // 494

    // Diagnostic round: three profiled probes (>176 us each via R=4 so they
    // enter the rocprof top-5). v_full runs LAST and writes correct output.
    v_store<<<grid, EBLOCK, SMEM_BYTES, stream>>>(out, E, 4);
    v_noexp<<<grid, EBLOCK, SMEM_BYTES, stream>>>(e_rbf, z, nbr, (const float*)d_ws, out, E, 4);
    v_full <<<grid, EBLOCK, SMEM_BYTES, stream>>>(e_rbf, z, nbr, (const float*)d_ws, out, E, 4);
}

// Round 12
// 80.401 us; speedup vs baseline: 12.8487x; 12.8487x over previous
//
#include <hip/hip_runtime.h>
#include <hip/hip_fp16.h>

#define EMBED 128
#define NRBF 6
#define VOCAB 100
#define EBLOCK 1024
#define GROUPS 32                   // 32-lane groups per block
#define CPG 38                      // edges per group (whole chunk, no halves)
#define BCHUNK (GROUPS * CPG)       // 1216 edges per block
#define T_HALFS (VOCAB * EMBED)                            // 12800 halfs/table
#define TABLE_BYTES (2 * T_HALFS * 2 + NRBF * EMBED * 4)   // 54,272 B
#define SMEM_BYTES (TABLE_BYTES + BCHUNK * 16)             // 73,728 B -> 2 blocks/CU

// ---------------------------------------------------------------------------
// Precompute (206 blocks): T1h/T2h fp16 tables (+bias folded in T1), Wc fp32.
//   T1h[v][d] = fp16( sum_j emb[v][j]*Wd[j][d] + b[d] )
//   T2h[v][d] = fp16( sum_j emb[v][j]*Wd[128+j][d] )
//   Wc[k][d]  = sum_j W_edge[k][j]*Wd[256+j][d]
// ---------------------------------------------------------------------------
__global__ __launch_bounds__(EMBED) void precompute_kernel(
    const float* __restrict__ W_edge,
    const float* __restrict__ emb,
    const float* __restrict__ Wd,
    const float* __restrict__ b,
    __half* __restrict__ T1h,
    __half* __restrict__ T2h,
    float* __restrict__ Wc)
{
    const int d = threadIdx.x;
    const int v = blockIdx.x;
    if (v < 2 * VOCAB) {
        const int row = (v < VOCAB) ? v : v - VOCAB;
        const int woff = (v < VOCAB) ? 0 : EMBED;
        __shared__ float hrow[EMBED];
        hrow[d] = emb[row * EMBED + d];
        __syncthreads();
        float acc = (v < VOCAB) ? b[d] : 0.0f;
        #pragma unroll 8
        for (int j = 0; j < EMBED; ++j)
            acc += hrow[j] * Wd[(woff + j) * EMBED + d];
        if (v < VOCAB) T1h[row * EMBED + d] = __float2half_rn(acc);
        else           T2h[row * EMBED + d] = __float2half_rn(acc);
    } else {
        const int k = v - 2 * VOCAB;
        float acc = 0.0f;
        #pragma unroll 8
        for (int j = 0; j < EMBED; ++j)
            acc += W_edge[k * EMBED + j] * Wd[(2 * EMBED + j) * EMBED + d];
        Wc[k * EMBED + d] = acc;
    }
}

// ---------------------------------------------------------------------------
// Edge kernel — ONE-BARRIER structure.
// Stage phase: tables (54 KB) + meta for ALL 1216 edges of the block
//   {6x fp16 rbf, z[a]|z[b]<<16} -> LDS.  __syncthreads (the only one).
// Consume phase: 38 edges/group, LDS reads + FMA + silu + contiguous 1 KB
//   wave stores.  NO further barriers -> the store queue is never drained
//   mid-kernel (each __syncthreads costs a s_waitcnt vmcnt(0) store drain).
// 73.7 KB LDS -> 2 blocks/CU: one block's stage hides under the other's
// store stream.
// ---------------------------------------------------------------------------
__global__ __launch_bounds__(EBLOCK, 8) void edge_kernel(
    const float* __restrict__ e_rbf,   // [E,6]
    const int*   __restrict__ z,       // [N]
    const int*   __restrict__ nbr,     // [E,2]
    const float* __restrict__ tables,  // T1h|T2h|Wc in ws
    float* __restrict__ out,           // [E,128]
    int E)
{
    extern __shared__ char smemraw[];
    __half* T1s  = (__half*)smemraw;                    // [12800]
    __half* T2s  = T1s + T_HALFS;                       // [12800]
    float*  Wcs  = (float*)(smemraw + 2 * T_HALFS * 2); // [768]
    uint4*  meta = (uint4*)(smemraw + TABLE_BYTES);     // [1216]

    const int tid  = threadIdx.x;
    const int base = blockIdx.x * BCHUNK;
    const int lane = tid & 31;
    const int d    = lane * 4;
    const int g    = tid >> 5;

    // ---- stage tables ----
    {
        const float4* src = reinterpret_cast<const float4*>(tables);
        float4* dst = reinterpret_cast<float4*>(smemraw);
        #pragma unroll 4
        for (int i = tid; i < TABLE_BYTES / 16; i += EBLOCK)
            dst[i] = src[i];
    }
    // ---- stage meta for the whole chunk ----
    #pragma unroll 2
    for (int idx = tid; idx < BCHUNK; idx += EBLOCK) {
        const int e = base + idx;
        uint4 m = make_uint4(0u, 0u, 0u, 0u);
        if (e < E) {
            const int2 nn = *reinterpret_cast<const int2*>(nbr + 2 * e);
            const float* rp = e_rbf + (long)e * NRBF;
            const float2 a  = *reinterpret_cast<const float2*>(rp + 0);
            const float2 bb = *reinterpret_cast<const float2*>(rp + 2);
            const float2 c  = *reinterpret_cast<const float2*>(rp + 4);
            __half2 ha = __float22half2_rn(a);
            __half2 hb = __float22half2_rn(bb);
            __half2 hc = __float22half2_rn(c);
            m.x = *reinterpret_cast<unsigned*>(&ha);
            m.y = *reinterpret_cast<unsigned*>(&hb);
            m.z = *reinterpret_cast<unsigned*>(&hc);
            m.w = (unsigned)z[nn.x] | ((unsigned)z[nn.y] << 16);
        }
        meta[idx] = m;
    }
    __syncthreads();   // the ONLY barrier

    // Wc into registers (invariant)
    const float4 wc0 = *reinterpret_cast<const float4*>(Wcs + 0 * EMBED + d);
    const float4 wc1 = *reinterpret_cast<const float4*>(Wcs + 1 * EMBED + d);
    const float4 wc2 = *reinterpret_cast<const float4*>(Wcs + 2 * EMBED + d);
    const float4 wc3 = *reinterpret_cast<const float4*>(Wcs + 3 * EMBED + d);
    const float4 wc4 = *reinterpret_cast<const float4*>(Wcs + 4 * EMBED + d);
    const float4 wc5 = *reinterpret_cast<const float4*>(Wcs + 5 * EMBED + d);

    // ---- consume: pair-mapped groups -> each wave stores 1 KB contiguous ----
    const int lb = (g >> 1) * (2 * CPG) + (g & 1);
    #pragma unroll 4
    for (int i = 0; i < CPG; ++i) {
        const int le = lb + 2 * i;
        const int e = base + le;

        const uint4 m = meta[le];                    // ds_read_b128 broadcast
        const int za = (int)(m.w & 0xffffu) << 7;
        const int zb = (int)(m.w >> 16) << 7;

        const uint2 t1p = *reinterpret_cast<const uint2*>(T1s + za + d);
        const uint2 t2p = *reinterpret_cast<const uint2*>(T2s + zb + d);
        const __half2 s0 = __hadd2(*reinterpret_cast<const __half2*>(&t1p.x),
                                   *reinterpret_cast<const __half2*>(&t2p.x));
        const __half2 s1 = __hadd2(*reinterpret_cast<const __half2*>(&t1p.y),
                                   *reinterpret_cast<const __half2*>(&t2p.y));
        const float2 a01 = __half22float2(s0);
        const float2 a23 = __half22float2(s1);
        float4 acc = make_float4(a01.x, a01.y, a23.x, a23.y);

        const float2 f01 = __half22float2(*reinterpret_cast<const __half2*>(&m.x));
        const float2 f23 = __half22float2(*reinterpret_cast<const __half2*>(&m.y));
        const float2 f45 = __half22float2(*reinterpret_cast<const __half2*>(&m.z));

        acc.x += f01.x * wc0.x; acc.y += f01.x * wc0.y; acc.z += f01.x * wc0.z; acc.w += f01.x * wc0.w;
        acc.x += f01.y * wc1.x; acc.y += f01.y * wc1.y; acc.z += f01.y * wc1.z; acc.w += f01.y * wc1.w;
        acc.x += f23.x * wc2.x; acc.y += f23.x * wc2.y; acc.z += f23.x * wc2.z; acc.w += f23.x * wc2.w;
        acc.x += f23.y * wc3.x; acc.y += f23.y * wc3.y; acc.z += f23.y * wc3.z; acc.w += f23.y * wc3.w;
        acc.x += f45.x * wc4.x; acc.y += f45.x * wc4.y; acc.z += f45.x * wc4.z; acc.w += f45.x * wc4.w;
        acc.x += f45.y * wc5.x; acc.y += f45.y * wc5.y; acc.z += f45.y * wc5.z; acc.w += f45.y * wc5.w;

        float4 rr;
        rr.x = acc.x * __builtin_amdgcn_rcpf(1.0f + __expf(-acc.x));
        rr.y = acc.y * __builtin_amdgcn_rcpf(1.0f + __expf(-acc.y));
        rr.z = acc.z * __builtin_amdgcn_rcpf(1.0f + __expf(-acc.z));
        rr.w = acc.w * __builtin_amdgcn_rcpf(1.0f + __expf(-acc.w));

        if (e < E)
            *reinterpret_cast<float4*>(out + (long)e * EMBED + d) = rr;
    }
}

extern "C" void kernel_launch(void* const* d_in, const int* in_sizes, int n_in,
                              void* d_out, int out_size, void* d_ws, size_t ws_size,
                              hipStream_t stream)
{
    // Input order: e_rbf, z, nbr_list, W_edge, emb_table, W_dense, b_dense
    const float* e_rbf  = (const float*)d_in[0];
    const int*   z      = (const int*)  d_in[1];
    const int*   nbr    = (const int*)  d_in[2];
    const float* W_edge = (const float*)d_in[3];
    const float* emb    = (const float*)d_in[4];
    const float* Wd     = (const float*)d_in[5];
    const float* b      = (const float*)d_in[6];
    float* out = (float*)d_out;

    const int E = in_sizes[2] / 2;

    __half* T1h = (__half*)d_ws;
    __half* T2h = T1h + T_HALFS;
    float*  Wc  = (float*)((char*)d_ws + 2 * T_HALFS * 2);

    precompute_kernel<<<2 * VOCAB + NRBF, EMBED, 0, stream>>>(W_edge, emb, Wd, b, T1h, T2h, Wc);

    const int grid = (E + BCHUNK - 1) / BCHUNK;   // 494 for E=600000
    edge_kernel<<<grid, EBLOCK, SMEM_BYTES, stream>>>(e_rbf, z, nbr, (const float*)d_ws, out, E);
}